// Round 4
// baseline (1354.266 us; speedup 1.0000x reference)
//
#include <hip/hip_runtime.h>

#define PD 64
#define BIN_C 6144   // edges staged per block in k_bin (48KB LDS)
#define RB 512       // nodes per bucket (log2 = 9)

// ---------------- phase 1: bin edges by bucket (locality-preserving) ----------------
__global__ __launch_bounds__(256) void k_bin(const int* __restrict__ ei,
    const float* __restrict__ w, uint2* __restrict__ bkt_in, uint2* __restrict__ bkt_out,
    int* __restrict__ bcnt, int E, int K, int cap) {
  __shared__ uint2 staged[BIN_C];
  __shared__ unsigned short bin16[BIN_C];
  __shared__ int cnt[256], base[257], off[256];
  int dir = blockIdx.y;
  const int* __restrict__ keys = dir ? ei : ei + E;
  const int* __restrict__ vals = dir ? ei + E : ei;
  uint2* __restrict__ bdst = dir ? bkt_out : bkt_in;
  int tid = threadIdx.x;
  int e0 = blockIdx.x * BIN_C;
  int count = min(BIN_C, E - e0);
  cnt[tid] = 0;
  __syncthreads();
  for (int i = tid; i < count; i += 256) {
    int b = keys[e0 + i] >> 9;
    bin16[i] = (unsigned short)b;
    atomicAdd(&cnt[b], 1);
  }
  __syncthreads();
  int v = cnt[tid];
  off[tid] = v;
  __syncthreads();
  for (int o = 1; o < 256; o <<= 1) {
    int t = (tid >= o) ? off[tid - o] : 0;
    __syncthreads();
    off[tid] += t;
    __syncthreads();
  }
  base[tid] = off[tid] - v;
  if (tid == 255) base[256] = off[255];
  __syncthreads();
  off[tid] = 0;
  __syncthreads();
  for (int i = tid; i < count; i += 256) {
    int e = e0 + i;
    int k = keys[e];
    int b = bin16[i];
    int l = k & (RB - 1);
    unsigned int packed = ((unsigned int)vals[e] << 9) | (unsigned int)l;
    int p = base[b] + atomicAdd(&off[b], 1);
    staged[p] = make_uint2(packed, __float_as_uint(w[e]));
  }
  __syncthreads();
  if (tid < K) {
    int c = cnt[tid];
    off[tid] = c > 0 ? atomicAdd(&bcnt[dir * K + tid], c) : 0;
  }
  __syncthreads();
  for (int i = tid; i < count; i += 256) {
    int lo = 0, hi = K;
    while (hi - lo > 1) { int mid = (lo + hi) >> 1; if (base[mid] <= i) lo = mid; else hi = mid; }
    int b = lo;
    int rel = off[b] + (i - base[b]);
    if (rel < cap) bdst[(size_t)b * cap + rel] = staged[i];
  }
}

// ---------------- phase 2: per-bucket local CSR ----------------
__global__ __launch_bounds__(256) void k_bucket(
    const uint2* __restrict__ bkt_in, const uint2* __restrict__ bkt_out,
    const int* __restrict__ bcnt,
    int* __restrict__ beg_in, int* __restrict__ end_in,
    int* __restrict__ beg_out, int* __restrict__ end_out,
    float* __restrict__ sw_in, float* __restrict__ sw_out,
    int* __restrict__ col_in, int* __restrict__ col_out,
    int cap, int N, int K) {
  __shared__ int deg[RB], pos[RB], off[RB];
  __shared__ float swl[RB];
  __shared__ int ps[256];
  int b = blockIdx.x, dir = blockIdx.y, tid = threadIdx.x;
  const uint2* __restrict__ bkt = (dir ? bkt_out : bkt_in) + (size_t)b * cap;
  int* __restrict__ beg = dir ? beg_out : beg_in;
  int* __restrict__ end = dir ? end_out : end_in;
  float* __restrict__ swg = dir ? sw_out : sw_in;
  int* __restrict__ col = dir ? col_out : col_in;
  int len = bcnt[dir * K + b];
  if (len > cap) len = cap;
  deg[tid] = 0; deg[tid + 256] = 0;
  swl[tid] = 0.f; swl[tid + 256] = 0.f;
  __syncthreads();
  for (int i = tid; i < len; i += 256) {
    uint2 u = bkt[i];
    int l = u.x & (RB - 1);
    atomicAdd(&deg[l], 1);
    atomicAdd(&swl[l], __uint_as_float(u.y));
  }
  __syncthreads();
  int a0 = deg[2 * tid], a1 = deg[2 * tid + 1];
  ps[tid] = a0 + a1;
  __syncthreads();
  for (int o = 1; o < 256; o <<= 1) {
    int t = (tid >= o) ? ps[tid - o] : 0;
    __syncthreads();
    ps[tid] += t;
    __syncthreads();
  }
  int ex = ps[tid] - (a0 + a1);
  pos[2 * tid] = ex;
  pos[2 * tid + 1] = ex + a0;
  off[tid] = 0; off[tid + 256] = 0;
  __syncthreads();
  int base_node = b << 9;
  size_t colbase = (size_t)b * cap;
  for (int l = tid; l < RB; l += 256) {
    int g = base_node + l;
    if (g < N) {
      beg[g] = (int)(colbase + pos[l]);
      end[g] = (int)(colbase + pos[l] + deg[l]);
      swg[g] = swl[l];
    }
  }
  __syncthreads();
  for (int i = tid; i < len; i += 256) {
    uint2 u = bkt[i];
    int l = u.x & (RB - 1);
    int s = (int)(u.x >> 9);
    int p = pos[l] + atomicAdd(&off[l], 1);
    col[colbase + p] = s;
  }
}

// ---------------- per-step weight folding ----------------
__global__ void k_wprep(const float* __restrict__ W1, const float* __restrict__ W2,
                        const float* __restrict__ W3, const float* __restrict__ W4,
                        const float* __restrict__ Wc1, const float* __restrict__ Wc2,
                        const float* __restrict__ Wcomp, const float* __restrict__ W7,
                        float* c1, float* c3, float* Mt, float* Wc2t,
                        float* WcompT, float* W7t) {
  int t = blockIdx.x;
  int tid = threadIdx.x;
  __shared__ float r4[64], v3[64];
  if (tid < 64) r4[tid] = fmaxf(W4[t * 64 + tid], 0.f);
  __syncthreads();
  if (tid < 64) {
    float s = 0.f;
    for (int k = 0; k < 64; ++k) s += W3[t * 4096 + tid * 64 + k] * r4[k];
    v3[tid] = s;
    float s1 = 0.f;
    for (int k = 0; k < 64; ++k) s1 += Wc1[t * 12288 + tid * 192 + k] * W1[t * 64 + k];
    c1[t * 64 + tid] = s1;
  }
  __syncthreads();
  if (tid < 64) {
    float s = 0.f;
    for (int k = 0; k < 64; ++k) s += Wc1[t * 12288 + tid * 192 + 128 + k] * v3[k];
    c3[t * 64 + tid] = s;
  }
  for (int idx = tid; idx < 4096; idx += 256) {
    int j = idx >> 6, p = idx & 63;
    float s = 0.f;
    for (int k = 0; k < 64; ++k)
      s += Wc1[t * 12288 + p * 192 + 64 + k] * W2[t * 4096 + k * 64 + j];
    Mt[t * 4096 + idx] = s;
    Wc2t[t * 4096 + idx] = Wc2[t * 4096 + p * 64 + j];
  }
  if (t == 0) {
    for (int idx = tid; idx < 8192; idx += 256) {
      int j = idx >> 6, p = idx & 63;
      WcompT[idx] = Wcomp[p * 128 + j];
    }
    for (int idx = tid; idx < 4096; idx += 256) {
      int j = idx >> 6, p = idx & 63;
      W7t[idx] = W7[p * 64 + j];
    }
  }
}

// ---------------- edge aggregation (gather over CSR, ILP=8) ----------------
__global__ __launch_bounds__(256) void k_agg(
    const int* __restrict__ beg_in, const int* __restrict__ end_in,
    const int* __restrict__ col_in,
    const int* __restrict__ beg_out, const int* __restrict__ end_out,
    const int* __restrict__ col_out,
    const float* __restrict__ mu, float* __restrict__ agg_in,
    float* __restrict__ agg_out, int n) {
  int wave = (blockIdx.x * blockDim.x + threadIdx.x) >> 6;
  int lane = threadIdx.x & 63;
  if (wave >= n) return;
#pragma unroll
  for (int dir = 0; dir < 2; ++dir) {
    const int* __restrict__ bega = dir ? beg_out : beg_in;
    const int* __restrict__ enda = dir ? end_out : end_in;
    const int* __restrict__ col = dir ? col_out : col_in;
    float* __restrict__ agg = dir ? agg_out : agg_in;
    int b = bega[wave], e = enda[wave];
    float a0 = 0.f, a1 = 0.f, a2 = 0.f, a3 = 0.f;
    if (b < e) {
      int last = e - 1;
      for (int k = b; k < e; k += 8) {
        int idx[8];
        float msk[8];
#pragma unroll
        for (int i = 0; i < 8; ++i) {
          int kk = k + i;
          idx[i] = col[kk <= last ? kk : last];
          msk[i] = (kk <= last) ? 1.f : 0.f;
        }
        float v[8];
#pragma unroll
        for (int i = 0; i < 8; ++i)
          v[i] = mu[(size_t)idx[i] * 64 + lane];
        a0 = fmaf(msk[0], v[0], a0);
        a1 = fmaf(msk[1], v[1], a1);
        a2 = fmaf(msk[2], v[2], a2);
        a3 = fmaf(msk[3], v[3], a3);
        a0 = fmaf(msk[4], v[4], a0);
        a1 = fmaf(msk[5], v[5], a1);
        a2 = fmaf(msk[6], v[6], a2);
        a3 = fmaf(msk[7], v[7], a3);
      }
    }
    agg[(size_t)wave * 64 + lane] = (a0 + a1) + (a2 + a3);
  }
}

// ---------------- fused per-node GEMM chain: lane = node ----------------
// All 64 output accumulators live in statically-indexed registers; weights are
// wave-uniform -> float4 LDS broadcasts (conflict-free). Intermediates round-trip
// through each wave's PRIVATE 16KB chunk of agg_in/agg_out/mu (transposed tile,
// coalesced 256B ops, L2-hot). Summation order per output matches the reference.
__device__ __forceinline__ void gemm64(const float* wlds, const float* src,
                                       int jstride, float acc[64]) {
#pragma unroll 4
  for (int j = 0; j < 64; ++j) {
    float aj = src[(size_t)j * jstride];
    const float4* wr = (const float4*)(wlds + j * 64);
#pragma unroll
    for (int q = 0; q < 16; ++q) {
      float4 wv = wr[q];
      acc[4 * q + 0] = fmaf(aj, wv.x, acc[4 * q + 0]);
      acc[4 * q + 1] = fmaf(aj, wv.y, acc[4 * q + 1]);
      acc[4 * q + 2] = fmaf(aj, wv.z, acc[4 * q + 2]);
      acc[4 * q + 3] = fmaf(aj, wv.w, acc[4 * q + 3]);
    }
  }
}

__global__ __launch_bounds__(256, 2) void k_node(
    const float* __restrict__ x, const float* __restrict__ sw_in,
    const float* __restrict__ sw_out, float* agg_in, float* agg_out,
    const float* __restrict__ c1g, const float* __restrict__ c3g,
    const float* __restrict__ Mtg, const float* __restrict__ Wc2tg,
    const float* __restrict__ WcompTg, float* mu, int n, int t, int haveAgg) {
  __shared__ float sM[4096], sC2[4096], sCmp[8192], sc1[64], sc3[64];
  int tid = threadIdx.x;
  {
    const float4* a = (const float4*)(Mtg + t * 4096);
    const float4* b = (const float4*)(Wc2tg + t * 4096);
    const float4* c = (const float4*)WcompTg;
    float4* pa = (float4*)sM;
    float4* pb = (float4*)sC2;
    float4* pc = (float4*)sCmp;
    for (int i = tid; i < 1024; i += 256) { pa[i] = a[i]; pb[i] = b[i]; }
    for (int i = tid; i < 2048; i += 256) pc[i] = c[i];
    if (tid < 64) { sc1[tid] = c1g[t * 64 + tid]; sc3[tid] = c3g[t * 64 + tid]; }
  }
  __syncthreads();
  int lane = tid & 63, w = tid >> 6;
  int node0 = (blockIdx.x * 4 + w) * 64;
  if (node0 >= n) return;
  int nd = node0 + lane;
  bool act = nd < n;
  int nc = act ? nd : n - 1;
  float xv = act ? x[nc] : 0.f;
  float acc[64];

  float* zt = agg_in + (size_t)node0 * 64;   // wave-private scratch tile
  float* mi = mu + (size_t)node0 * 64;       // holds m_in, later final mu
  float* mo = agg_out + (size_t)node0 * 64;  // holds m_out after dir1 gather done

  // ---- dir 0 (in) ----
  {
    float swv = act ? sw_in[nc] : 0.f;
#pragma unroll
    for (int p = 0; p < 64; ++p) acc[p] = xv * sc1[p] + swv * sc3[p];
    if (haveAgg) gemm64(sM, agg_in + (size_t)nc * 64, 1, acc);
#pragma unroll
    for (int p = 0; p < 64; ++p) zt[p * 64 + lane] = fmaxf(acc[p], 0.f);
#pragma unroll
    for (int p = 0; p < 64; ++p) acc[p] = 0.f;
    gemm64(sC2, zt + lane, 64, acc);
#pragma unroll
    for (int p = 0; p < 64; ++p) mi[p * 64 + lane] = fmaxf(acc[p], 0.f);
  }
  // ---- dir 1 (out) ----
  {
    float swv = act ? sw_out[nc] : 0.f;
#pragma unroll
    for (int p = 0; p < 64; ++p) acc[p] = xv * sc1[p] + swv * sc3[p];
    if (haveAgg) gemm64(sM, agg_out + (size_t)nc * 64, 1, acc);
#pragma unroll
    for (int p = 0; p < 64; ++p) zt[p * 64 + lane] = fmaxf(acc[p], 0.f);
#pragma unroll
    for (int p = 0; p < 64; ++p) acc[p] = 0.f;
    gemm64(sC2, zt + lane, 64, acc);
#pragma unroll
    for (int p = 0; p < 64; ++p) mo[p * 64 + lane] = fmaxf(acc[p], 0.f);
  }
  // ---- compress ----
#pragma unroll
  for (int p = 0; p < 64; ++p) acc[p] = 0.f;
  gemm64(sCmp, mi + lane, 64, acc);
  gemm64(sCmp + 4096, mo + lane, 64, acc);
  if (act) {
    float4* dst = (float4*)(mu + (size_t)nd * 64);
#pragma unroll
    for (int q = 0; q < 16; ++q)
      dst[q] = make_float4(fmaxf(acc[4 * q + 0], 0.f), fmaxf(acc[4 * q + 1], 0.f),
                           fmaxf(acc[4 * q + 2], 0.f), fmaxf(acc[4 * q + 3], 0.f));
  }
}

// ---------------- pooling ----------------
__global__ __launch_bounds__(256) void k_pool(
    const float* __restrict__ mu, const int* __restrict__ batch,
    float* __restrict__ pool, int n) {
  int gw = (blockIdx.x * blockDim.x + threadIdx.x) >> 6;
  int lane = threadIdx.x & 63;
  int start = gw * 256;
  if (start >= n) return;
  int end = min(start + 256, n);
  int cur = batch[start];
  float acc = 0.f;
  for (int i = start; i < end; ++i) {
    int b = batch[i];
    if (b != cur) {
      atomicAdd(&pool[cur * 64 + lane], acc);
      acc = 0.f;
      cur = b;
    }
    acc += mu[(size_t)i * 64 + lane];
  }
  atomicAdd(&pool[cur * 64 + lane], acc);
}

__global__ void k_poolw6(const float* __restrict__ pool, const float* __restrict__ W6,
                         float* __restrict__ out) {
  int idx = blockIdx.x * blockDim.x + threadIdx.x;  // < 4096
  int g = idx >> 6, p = idx & 63;
  float s = 0.f;
  for (int k = 0; k < 64; ++k) s += pool[g * 64 + k] * W6[p * 64 + k];
  out[idx] = s;
}

// ---------------- head ----------------
__global__ __launch_bounds__(256) void k_final(
    const float* __restrict__ mu, const int* __restrict__ batch,
    const float* __restrict__ poolw6, const float* __restrict__ W7t,
    const float* __restrict__ W5, float* __restrict__ out, int n) {
  __shared__ float S[4][64];
  int tid = threadIdx.x, lane = tid & 63, w = tid >> 6;
  int node = blockIdx.x * 4 + w;
  if (node >= n) return;
  float mv = mu[(size_t)node * 64 + lane];
  S[w][lane] = mv;
  __builtin_amdgcn_wave_barrier();
  int g = batch[node];
  float t1 = fmaxf(poolw6[g * 64 + lane], 0.f);
  float acc = 0.f;
#pragma unroll 8
  for (int j = 0; j < 64; ++j) acc = fmaf(S[w][j], W7t[j * 64 + lane], acc);
  float t2 = fmaxf(acc, 0.f);
  float val = W5[lane] * t1 + W5[64 + lane] * t2;
  for (int off = 32; off > 0; off >>= 1) val += __shfl_down(val, off);
  if (lane == 0) out[node] = fmaxf(val, 0.f);
}

extern "C" void kernel_launch(void* const* d_in, const int* in_sizes, int n_in,
                              void* d_out, int out_size, void* d_ws, size_t ws_size,
                              hipStream_t stream) {
  const float* x = (const float*)d_in[0];
  const float* weight = (const float*)d_in[1];
  const int* ei = (const int*)d_in[2];
  const int* batch = (const int*)d_in[3];
  const float* W1 = (const float*)d_in[4];
  const float* W2 = (const float*)d_in[5];
  const float* W3 = (const float*)d_in[6];
  const float* W4 = (const float*)d_in[7];
  const float* Wc1 = (const float*)d_in[8];
  const float* Wc2 = (const float*)d_in[9];
  const float* Wcomp = (const float*)d_in[10];
  const float* W5 = (const float*)d_in[11];
  const float* W6 = (const float*)d_in[12];
  const float* W7 = (const float*)d_in[13];
  float* out = (float*)d_out;
  int N = in_sizes[0];
  int E = in_sizes[1];
  int T = in_sizes[4] / 64;

  int K = (N + RB - 1) / RB;
  int cap = E / K + E / (4 * K) + 1024;
  int Nw = ((N + 63) / 64) * 64;   // node count padded to whole waves

  char* ws = (char*)d_ws;
  size_t off = 0;
  auto alloc = [&](size_t bytes) {
    size_t o = off;
    off += (bytes + 255) & ~(size_t)255;
    return o;
  };
  // zeroed region
  size_t o_bcnt = alloc((size_t)2 * K * 4);
  size_t o_pool = alloc(4096 * 4);
  size_t zero_end = off;
  size_t o_beg_in = alloc((size_t)N * 4);
  size_t o_end_in = alloc((size_t)N * 4);
  size_t o_beg_out = alloc((size_t)N * 4);
  size_t o_end_out = alloc((size_t)N * 4);
  size_t o_sw_in = alloc((size_t)N * 4);
  size_t o_sw_out = alloc((size_t)N * 4);
  size_t o_col_in = alloc((size_t)K * cap * 4);
  size_t o_col_out = alloc((size_t)K * cap * 4);
  size_t o_mu = alloc((size_t)Nw * 64 * 4);
  size_t aggBytes = (size_t)Nw * 64 * 4;
  size_t bktBytes = (size_t)K * cap * 8;
  size_t big = aggBytes > bktBytes ? aggBytes : bktBytes;
  size_t o_agg_in = alloc(big);   // aliased: bkt_in during build
  size_t o_agg_out = alloc(big);  // aliased: bkt_out during build
  size_t o_c1 = alloc(4 * 64 * 4);
  size_t o_c3 = alloc(4 * 64 * 4);
  size_t o_Mt = alloc(4 * 4096 * 4);
  size_t o_Wc2t = alloc(4 * 4096 * 4);
  size_t o_WcompT = alloc(8192 * 4);
  size_t o_W7t = alloc(4096 * 4);
  size_t o_poolw6 = alloc(4096 * 4);
  (void)ws_size; (void)n_in; (void)out_size;

  hipMemsetAsync(ws, 0, zero_end, stream);

  dim3 gBin((E + BIN_C - 1) / BIN_C, 2);
  k_bin<<<gBin, 256, 0, stream>>>(ei, weight, (uint2*)(ws + o_agg_in),
                                  (uint2*)(ws + o_agg_out), (int*)(ws + o_bcnt),
                                  E, K, cap);
  dim3 gBkt(K, 2);
  k_bucket<<<gBkt, 256, 0, stream>>>((uint2*)(ws + o_agg_in), (uint2*)(ws + o_agg_out),
                                     (int*)(ws + o_bcnt),
                                     (int*)(ws + o_beg_in), (int*)(ws + o_end_in),
                                     (int*)(ws + o_beg_out), (int*)(ws + o_end_out),
                                     (float*)(ws + o_sw_in), (float*)(ws + o_sw_out),
                                     (int*)(ws + o_col_in), (int*)(ws + o_col_out),
                                     cap, N, K);
  k_wprep<<<T, 256, 0, stream>>>(W1, W2, W3, W4, Wc1, Wc2, Wcomp, W7,
                                 (float*)(ws + o_c1), (float*)(ws + o_c3),
                                 (float*)(ws + o_Mt), (float*)(ws + o_Wc2t),
                                 (float*)(ws + o_WcompT), (float*)(ws + o_W7t));

  int gN4 = (N + 3) / 4;
  int gNode = (N + 255) / 256;
  for (int t = 0; t < T; ++t) {
    if (t > 0)
      k_agg<<<gN4, 256, 0, stream>>>((int*)(ws + o_beg_in), (int*)(ws + o_end_in),
                                     (int*)(ws + o_col_in),
                                     (int*)(ws + o_beg_out), (int*)(ws + o_end_out),
                                     (int*)(ws + o_col_out),
                                     (float*)(ws + o_mu), (float*)(ws + o_agg_in),
                                     (float*)(ws + o_agg_out), N);
    k_node<<<gNode, 256, 0, stream>>>(x, (float*)(ws + o_sw_in), (float*)(ws + o_sw_out),
                                      (float*)(ws + o_agg_in), (float*)(ws + o_agg_out),
                                      (float*)(ws + o_c1), (float*)(ws + o_c3),
                                      (float*)(ws + o_Mt), (float*)(ws + o_Wc2t),
                                      (float*)(ws + o_WcompT), (float*)(ws + o_mu),
                                      N, t, t > 0 ? 1 : 0);
  }
  int gPool = ((N + 255) / 256 + 3) / 4;
  k_pool<<<gPool, 256, 0, stream>>>((float*)(ws + o_mu), batch, (float*)(ws + o_pool), N);
  k_poolw6<<<16, 256, 0, stream>>>((float*)(ws + o_pool), W6, (float*)(ws + o_poolw6));
  k_final<<<gN4, 256, 0, stream>>>((float*)(ws + o_mu), batch, (float*)(ws + o_poolw6),
                                   (float*)(ws + o_W7t), W5, out, N);
}

// Round 5
// 1256.235 us; speedup vs baseline: 1.0780x; 1.0780x over previous
//
#include <hip/hip_runtime.h>

#define PD 64
#define BIN_C 6144   // edges staged per block in k_bin (48KB LDS)
#define RB 512       // nodes per bucket (log2 = 9)

// ---------------- phase 1: bin edges by bucket (locality-preserving) ----------------
__global__ __launch_bounds__(256) void k_bin(const int* __restrict__ ei,
    const float* __restrict__ w, uint2* __restrict__ bkt_in, uint2* __restrict__ bkt_out,
    int* __restrict__ bcnt, int E, int K, int cap) {
  __shared__ uint2 staged[BIN_C];
  __shared__ unsigned short bin16[BIN_C];
  __shared__ int cnt[256], base[257], off[256];
  int dir = blockIdx.y;
  const int* __restrict__ keys = dir ? ei : ei + E;
  const int* __restrict__ vals = dir ? ei + E : ei;
  uint2* __restrict__ bdst = dir ? bkt_out : bkt_in;
  int tid = threadIdx.x;
  int e0 = blockIdx.x * BIN_C;
  int count = min(BIN_C, E - e0);
  cnt[tid] = 0;
  __syncthreads();
  for (int i = tid; i < count; i += 256) {
    int b = keys[e0 + i] >> 9;
    bin16[i] = (unsigned short)b;
    atomicAdd(&cnt[b], 1);
  }
  __syncthreads();
  int v = cnt[tid];
  off[tid] = v;
  __syncthreads();
  for (int o = 1; o < 256; o <<= 1) {
    int t = (tid >= o) ? off[tid - o] : 0;
    __syncthreads();
    off[tid] += t;
    __syncthreads();
  }
  base[tid] = off[tid] - v;
  if (tid == 255) base[256] = off[255];
  __syncthreads();
  off[tid] = 0;
  __syncthreads();
  for (int i = tid; i < count; i += 256) {
    int e = e0 + i;
    int k = keys[e];
    int b = bin16[i];
    int l = k & (RB - 1);
    unsigned int packed = ((unsigned int)vals[e] << 9) | (unsigned int)l;
    int p = base[b] + atomicAdd(&off[b], 1);
    staged[p] = make_uint2(packed, __float_as_uint(w[e]));
  }
  __syncthreads();
  if (tid < K) {
    int c = cnt[tid];
    off[tid] = c > 0 ? atomicAdd(&bcnt[dir * K + tid], c) : 0;
  }
  __syncthreads();
  for (int i = tid; i < count; i += 256) {
    int lo = 0, hi = K;
    while (hi - lo > 1) { int mid = (lo + hi) >> 1; if (base[mid] <= i) lo = mid; else hi = mid; }
    int b = lo;
    int rel = off[b] + (i - base[b]);
    if (rel < cap) bdst[(size_t)b * cap + rel] = staged[i];
  }
}

// ---------------- phase 2: per-bucket local CSR ----------------
__global__ __launch_bounds__(256) void k_bucket(
    const uint2* __restrict__ bkt_in, const uint2* __restrict__ bkt_out,
    const int* __restrict__ bcnt,
    int* __restrict__ beg_in, int* __restrict__ end_in,
    int* __restrict__ beg_out, int* __restrict__ end_out,
    float* __restrict__ sw_in, float* __restrict__ sw_out,
    int* __restrict__ col_in, int* __restrict__ col_out,
    int cap, int N, int K) {
  __shared__ int deg[RB], pos[RB], off[RB];
  __shared__ float swl[RB];
  __shared__ int ps[256];
  int b = blockIdx.x, dir = blockIdx.y, tid = threadIdx.x;
  const uint2* __restrict__ bkt = (dir ? bkt_out : bkt_in) + (size_t)b * cap;
  int* __restrict__ beg = dir ? beg_out : beg_in;
  int* __restrict__ end = dir ? end_out : end_in;
  float* __restrict__ swg = dir ? sw_out : sw_in;
  int* __restrict__ col = dir ? col_out : col_in;
  int len = bcnt[dir * K + b];
  if (len > cap) len = cap;
  deg[tid] = 0; deg[tid + 256] = 0;
  swl[tid] = 0.f; swl[tid + 256] = 0.f;
  __syncthreads();
  for (int i = tid; i < len; i += 256) {
    uint2 u = bkt[i];
    int l = u.x & (RB - 1);
    atomicAdd(&deg[l], 1);
    atomicAdd(&swl[l], __uint_as_float(u.y));
  }
  __syncthreads();
  int a0 = deg[2 * tid], a1 = deg[2 * tid + 1];
  ps[tid] = a0 + a1;
  __syncthreads();
  for (int o = 1; o < 256; o <<= 1) {
    int t = (tid >= o) ? ps[tid - o] : 0;
    __syncthreads();
    ps[tid] += t;
    __syncthreads();
  }
  int ex = ps[tid] - (a0 + a1);
  pos[2 * tid] = ex;
  pos[2 * tid + 1] = ex + a0;
  off[tid] = 0; off[tid + 256] = 0;
  __syncthreads();
  int base_node = b << 9;
  size_t colbase = (size_t)b * cap;
  for (int l = tid; l < RB; l += 256) {
    int g = base_node + l;
    if (g < N) {
      beg[g] = (int)(colbase + pos[l]);
      end[g] = (int)(colbase + pos[l] + deg[l]);
      swg[g] = swl[l];
    }
  }
  __syncthreads();
  for (int i = tid; i < len; i += 256) {
    uint2 u = bkt[i];
    int l = u.x & (RB - 1);
    int s = (int)(u.x >> 9);
    int p = pos[l] + atomicAdd(&off[l], 1);
    col[colbase + p] = s;
  }
}

// ---------------- per-step weight folding ----------------
__global__ void k_wprep(const float* __restrict__ W1, const float* __restrict__ W2,
                        const float* __restrict__ W3, const float* __restrict__ W4,
                        const float* __restrict__ Wc1, const float* __restrict__ Wc2,
                        const float* __restrict__ Wcomp, const float* __restrict__ W7,
                        float* c1, float* c3, float* Mt, float* Wc2t,
                        float* WcompT, float* W7t) {
  int t = blockIdx.x;
  int tid = threadIdx.x;
  __shared__ float r4[64], v3[64];
  if (tid < 64) r4[tid] = fmaxf(W4[t * 64 + tid], 0.f);
  __syncthreads();
  if (tid < 64) {
    float s = 0.f;
    for (int k = 0; k < 64; ++k) s += W3[t * 4096 + tid * 64 + k] * r4[k];
    v3[tid] = s;
    float s1 = 0.f;
    for (int k = 0; k < 64; ++k) s1 += Wc1[t * 12288 + tid * 192 + k] * W1[t * 64 + k];
    c1[t * 64 + tid] = s1;
  }
  __syncthreads();
  if (tid < 64) {
    float s = 0.f;
    for (int k = 0; k < 64; ++k) s += Wc1[t * 12288 + tid * 192 + 128 + k] * v3[k];
    c3[t * 64 + tid] = s;
  }
  for (int idx = tid; idx < 4096; idx += 256) {
    int j = idx >> 6, p = idx & 63;
    float s = 0.f;
    for (int k = 0; k < 64; ++k)
      s += Wc1[t * 12288 + p * 192 + 64 + k] * W2[t * 4096 + k * 64 + j];
    Mt[t * 4096 + idx] = s;
    Wc2t[t * 4096 + idx] = Wc2[t * 4096 + p * 64 + j];
  }
  if (t == 0) {
    for (int idx = tid; idx < 8192; idx += 256) {
      int j = idx >> 6, p = idx & 63;
      WcompT[idx] = Wcomp[p * 128 + j];
    }
    for (int idx = tid; idx < 4096; idx += 256) {
      int j = idx >> 6, p = idx & 63;
      W7t[idx] = W7[p * 64 + j];
    }
  }
}

// ---------------- edge aggregation (gather over CSR, ILP=8) ----------------
__global__ __launch_bounds__(256) void k_agg(
    const int* __restrict__ beg_in, const int* __restrict__ end_in,
    const int* __restrict__ col_in,
    const int* __restrict__ beg_out, const int* __restrict__ end_out,
    const int* __restrict__ col_out,
    const float* __restrict__ mu, float* __restrict__ agg_in,
    float* __restrict__ agg_out, int n) {
  int wave = (blockIdx.x * blockDim.x + threadIdx.x) >> 6;
  int lane = threadIdx.x & 63;
  if (wave >= n) return;
#pragma unroll
  for (int dir = 0; dir < 2; ++dir) {
    const int* __restrict__ bega = dir ? beg_out : beg_in;
    const int* __restrict__ enda = dir ? end_out : end_in;
    const int* __restrict__ col = dir ? col_out : col_in;
    float* __restrict__ agg = dir ? agg_out : agg_in;
    int b = bega[wave], e = enda[wave];
    float a0 = 0.f, a1 = 0.f, a2 = 0.f, a3 = 0.f;
    if (b < e) {
      int last = e - 1;
      for (int k = b; k < e; k += 8) {
        int idx[8];
        float msk[8];
#pragma unroll
        for (int i = 0; i < 8; ++i) {
          int kk = k + i;
          idx[i] = col[kk <= last ? kk : last];
          msk[i] = (kk <= last) ? 1.f : 0.f;
        }
        float v[8];
#pragma unroll
        for (int i = 0; i < 8; ++i)
          v[i] = mu[(size_t)idx[i] * 64 + lane];
        a0 = fmaf(msk[0], v[0], a0);
        a1 = fmaf(msk[1], v[1], a1);
        a2 = fmaf(msk[2], v[2], a2);
        a3 = fmaf(msk[3], v[3], a3);
        a0 = fmaf(msk[4], v[4], a0);
        a1 = fmaf(msk[5], v[5], a1);
        a2 = fmaf(msk[6], v[6], a2);
        a3 = fmaf(msk[7], v[7], a3);
      }
    }
    agg[(size_t)wave * 64 + lane] = (a0 + a1) + (a2 + a3);
  }
}

// ---------------- fused per-node GEMM chain: lane = node, LDS z-tiles ----------------
// Each wave owns 64 nodes (lane = node) and a private 16KB transposed z-tile in LDS.
// Weights occupy ONE rotating 16KB LDS slot, restaged 6x per block between barriers.
// Accumulators z/m/o (64 each) are statically-indexed registers. Weight reads are
// wave-uniform ds_read_b128 broadcasts (conflict-free); tile reads/writes are
// stride-64 b32 = 2 lanes/bank (free). Summation order matches the reference.
__device__ __forceinline__ void stageW(float* sW, const float* g, int tid) {
  __syncthreads();   // all waves done reading previous sW contents
  float4* d = (float4*)sW;
  const float4* s = (const float4*)g;
  for (int i = tid; i < 1024; i += 256) d[i] = s[i];
  __syncthreads();   // new weights visible
}

__device__ __forceinline__ void gemm_row(const float* sW, const float4* ar, float acc[64]) {
  for (int q4 = 0; q4 < 16; ++q4) {
    float4 av = ar[q4];
    float a4[4] = {av.x, av.y, av.z, av.w};
#pragma unroll
    for (int k = 0; k < 4; ++k) {
      float a = a4[k];
      const float4* wr = (const float4*)(sW + (q4 * 4 + k) * 64);
#pragma unroll
      for (int p4 = 0; p4 < 16; ++p4) {
        float4 wv = wr[p4];
        acc[4 * p4 + 0] = fmaf(a, wv.x, acc[4 * p4 + 0]);
        acc[4 * p4 + 1] = fmaf(a, wv.y, acc[4 * p4 + 1]);
        acc[4 * p4 + 2] = fmaf(a, wv.z, acc[4 * p4 + 2]);
        acc[4 * p4 + 3] = fmaf(a, wv.w, acc[4 * p4 + 3]);
      }
    }
  }
}

__device__ __forceinline__ void gemm_tile(const float* sW, const float* tz, int lane,
                                          float acc[64]) {
#pragma unroll 2
  for (int j = 0; j < 64; ++j) {
    float a = tz[j * 64 + lane];
    const float4* wr = (const float4*)(sW + j * 64);
#pragma unroll
    for (int p4 = 0; p4 < 16; ++p4) {
      float4 wv = wr[p4];
      acc[4 * p4 + 0] = fmaf(a, wv.x, acc[4 * p4 + 0]);
      acc[4 * p4 + 1] = fmaf(a, wv.y, acc[4 * p4 + 1]);
      acc[4 * p4 + 2] = fmaf(a, wv.z, acc[4 * p4 + 2]);
      acc[4 * p4 + 3] = fmaf(a, wv.w, acc[4 * p4 + 3]);
    }
  }
}

__global__ __launch_bounds__(256, 2) void k_node(
    const float* __restrict__ x, const float* __restrict__ sw_in,
    const float* __restrict__ sw_out, const float* __restrict__ agg_in,
    const float* __restrict__ agg_out, const float* __restrict__ c1g,
    const float* __restrict__ c3g, const float* __restrict__ Mtg,
    const float* __restrict__ Wc2tg, const float* __restrict__ WcompTg,
    float* __restrict__ mu, int n, int t, int haveAgg) {
  __shared__ float sW[4096];
  __shared__ float tileZ[4][4096];   // 80KB total -> 2 blocks/CU
  int tid = threadIdx.x, lane = tid & 63, w = tid >> 6;
  int node0 = blockIdx.x * 256 + w * 64;
  int nd = node0 + lane;
  bool act = nd < n;
  int nc = act ? nd : n - 1;        // NO early return: syncthreads must stay uniform
  float xv = x[nc];
  float* tz = tileZ[w];
  const float* c1 = c1g + t * 64;
  const float* c3 = c3g + t * 64;
  float o[64], zz[64];

  // ---- dir 0 (in) ----
  {
    float swv = sw_in[nc];
#pragma unroll
    for (int p = 0; p < 64; ++p) zz[p] = xv * c1[p] + swv * c3[p];
    if (haveAgg) {                   // block-uniform branch: barriers inside are safe
      stageW(sW, Mtg + t * 4096, tid);
      gemm_row(sW, (const float4*)(agg_in + (size_t)nc * 64), zz);
    }
#pragma unroll
    for (int p = 0; p < 64; ++p) tz[p * 64 + lane] = fmaxf(zz[p], 0.f);
  }
  stageW(sW, Wc2tg + t * 4096, tid);
  {
#pragma unroll
    for (int p = 0; p < 64; ++p) zz[p] = 0.f;
    gemm_tile(sW, tz, lane, zz);
#pragma unroll
    for (int p = 0; p < 64; ++p) tz[p * 64 + lane] = fmaxf(zz[p], 0.f);
  }
  stageW(sW, WcompTg, tid);          // Wcomp rows 0..63 (m_in part)
  {
#pragma unroll
    for (int p = 0; p < 64; ++p) o[p] = 0.f;
    gemm_tile(sW, tz, lane, o);
  }
  // ---- dir 1 (out) ----
  {
    float swv = sw_out[nc];
#pragma unroll
    for (int p = 0; p < 64; ++p) zz[p] = xv * c1[p] + swv * c3[p];
    if (haveAgg) {
      stageW(sW, Mtg + t * 4096, tid);
      gemm_row(sW, (const float4*)(agg_out + (size_t)nc * 64), zz);
    }
#pragma unroll
    for (int p = 0; p < 64; ++p) tz[p * 64 + lane] = fmaxf(zz[p], 0.f);
  }
  stageW(sW, Wc2tg + t * 4096, tid);
  {
#pragma unroll
    for (int p = 0; p < 64; ++p) zz[p] = 0.f;
    gemm_tile(sW, tz, lane, zz);
#pragma unroll
    for (int p = 0; p < 64; ++p) tz[p * 64 + lane] = fmaxf(zz[p], 0.f);
  }
  stageW(sW, WcompTg + 4096, tid);   // Wcomp rows 64..127 (m_out part)
  gemm_tile(sW, tz, lane, o);

  if (act) {
    float4* dst = (float4*)(mu + (size_t)nd * 64);
#pragma unroll
    for (int q = 0; q < 16; ++q)
      dst[q] = make_float4(fmaxf(o[4 * q + 0], 0.f), fmaxf(o[4 * q + 1], 0.f),
                           fmaxf(o[4 * q + 2], 0.f), fmaxf(o[4 * q + 3], 0.f));
  }
}

// ---------------- pooling ----------------
__global__ __launch_bounds__(256) void k_pool(
    const float* __restrict__ mu, const int* __restrict__ batch,
    float* __restrict__ pool, int n) {
  int gw = (blockIdx.x * blockDim.x + threadIdx.x) >> 6;
  int lane = threadIdx.x & 63;
  int start = gw * 256;
  if (start >= n) return;
  int end = min(start + 256, n);
  int cur = batch[start];
  float acc = 0.f;
  for (int i = start; i < end; ++i) {
    int b = batch[i];
    if (b != cur) {
      atomicAdd(&pool[cur * 64 + lane], acc);
      acc = 0.f;
      cur = b;
    }
    acc += mu[(size_t)i * 64 + lane];
  }
  atomicAdd(&pool[cur * 64 + lane], acc);
}

__global__ void k_poolw6(const float* __restrict__ pool, const float* __restrict__ W6,
                         float* __restrict__ out) {
  int idx = blockIdx.x * blockDim.x + threadIdx.x;  // < 4096
  int g = idx >> 6, p = idx & 63;
  float s = 0.f;
  for (int k = 0; k < 64; ++k) s += pool[g * 64 + k] * W6[p * 64 + k];
  out[idx] = s;
}

// ---------------- head ----------------
__global__ __launch_bounds__(256) void k_final(
    const float* __restrict__ mu, const int* __restrict__ batch,
    const float* __restrict__ poolw6, const float* __restrict__ W7t,
    const float* __restrict__ W5, float* __restrict__ out, int n) {
  __shared__ float S[4][64];
  int tid = threadIdx.x, lane = tid & 63, w = tid >> 6;
  int node = blockIdx.x * 4 + w;
  if (node >= n) return;
  float mv = mu[(size_t)node * 64 + lane];
  S[w][lane] = mv;
  __builtin_amdgcn_wave_barrier();
  int g = batch[node];
  float t1 = fmaxf(poolw6[g * 64 + lane], 0.f);
  float acc = 0.f;
#pragma unroll 8
  for (int j = 0; j < 64; ++j) acc = fmaf(S[w][j], W7t[j * 64 + lane], acc);
  float t2 = fmaxf(acc, 0.f);
  float val = W5[lane] * t1 + W5[64 + lane] * t2;
  for (int off = 32; off > 0; off >>= 1) val += __shfl_down(val, off);
  if (lane == 0) out[node] = fmaxf(val, 0.f);
}

extern "C" void kernel_launch(void* const* d_in, const int* in_sizes, int n_in,
                              void* d_out, int out_size, void* d_ws, size_t ws_size,
                              hipStream_t stream) {
  const float* x = (const float*)d_in[0];
  const float* weight = (const float*)d_in[1];
  const int* ei = (const int*)d_in[2];
  const int* batch = (const int*)d_in[3];
  const float* W1 = (const float*)d_in[4];
  const float* W2 = (const float*)d_in[5];
  const float* W3 = (const float*)d_in[6];
  const float* W4 = (const float*)d_in[7];
  const float* Wc1 = (const float*)d_in[8];
  const float* Wc2 = (const float*)d_in[9];
  const float* Wcomp = (const float*)d_in[10];
  const float* W5 = (const float*)d_in[11];
  const float* W6 = (const float*)d_in[12];
  const float* W7 = (const float*)d_in[13];
  float* out = (float*)d_out;
  int N = in_sizes[0];
  int E = in_sizes[1];
  int T = in_sizes[4] / 64;

  int K = (N + RB - 1) / RB;
  int cap = E / K + E / (4 * K) + 1024;
  int Nw = ((N + 63) / 64) * 64;

  char* ws = (char*)d_ws;
  size_t off = 0;
  auto alloc = [&](size_t bytes) {
    size_t o = off;
    off += (bytes + 255) & ~(size_t)255;
    return o;
  };
  // zeroed region
  size_t o_bcnt = alloc((size_t)2 * K * 4);
  size_t o_pool = alloc(4096 * 4);
  size_t zero_end = off;
  size_t o_beg_in = alloc((size_t)N * 4);
  size_t o_end_in = alloc((size_t)N * 4);
  size_t o_beg_out = alloc((size_t)N * 4);
  size_t o_end_out = alloc((size_t)N * 4);
  size_t o_sw_in = alloc((size_t)N * 4);
  size_t o_sw_out = alloc((size_t)N * 4);
  size_t o_col_in = alloc((size_t)K * cap * 4);
  size_t o_col_out = alloc((size_t)K * cap * 4);
  size_t o_mu = alloc((size_t)Nw * 64 * 4);
  size_t aggBytes = (size_t)Nw * 64 * 4;
  size_t bktBytes = (size_t)K * cap * 8;
  size_t big = aggBytes > bktBytes ? aggBytes : bktBytes;
  size_t o_agg_in = alloc(big);   // aliased: bkt_in during build
  size_t o_agg_out = alloc(big);  // aliased: bkt_out during build
  size_t o_c1 = alloc(4 * 64 * 4);
  size_t o_c3 = alloc(4 * 64 * 4);
  size_t o_Mt = alloc(4 * 4096 * 4);
  size_t o_Wc2t = alloc(4 * 4096 * 4);
  size_t o_WcompT = alloc(8192 * 4);
  size_t o_W7t = alloc(4096 * 4);
  size_t o_poolw6 = alloc(4096 * 4);
  (void)ws_size; (void)n_in; (void)out_size;

  hipMemsetAsync(ws, 0, zero_end, stream);

  dim3 gBin((E + BIN_C - 1) / BIN_C, 2);
  k_bin<<<gBin, 256, 0, stream>>>(ei, weight, (uint2*)(ws + o_agg_in),
                                  (uint2*)(ws + o_agg_out), (int*)(ws + o_bcnt),
                                  E, K, cap);
  dim3 gBkt(K, 2);
  k_bucket<<<gBkt, 256, 0, stream>>>((uint2*)(ws + o_agg_in), (uint2*)(ws + o_agg_out),
                                     (int*)(ws + o_bcnt),
                                     (int*)(ws + o_beg_in), (int*)(ws + o_end_in),
                                     (int*)(ws + o_beg_out), (int*)(ws + o_end_out),
                                     (float*)(ws + o_sw_in), (float*)(ws + o_sw_out),
                                     (int*)(ws + o_col_in), (int*)(ws + o_col_out),
                                     cap, N, K);
  k_wprep<<<T, 256, 0, stream>>>(W1, W2, W3, W4, Wc1, Wc2, Wcomp, W7,
                                 (float*)(ws + o_c1), (float*)(ws + o_c3),
                                 (float*)(ws + o_Mt), (float*)(ws + o_Wc2t),
                                 (float*)(ws + o_WcompT), (float*)(ws + o_W7t));

  int gN4 = (N + 3) / 4;
  int gNode = (N + 255) / 256;
  for (int t = 0; t < T; ++t) {
    if (t > 0)
      k_agg<<<gN4, 256, 0, stream>>>((int*)(ws + o_beg_in), (int*)(ws + o_end_in),
                                     (int*)(ws + o_col_in),
                                     (int*)(ws + o_beg_out), (int*)(ws + o_end_out),
                                     (int*)(ws + o_col_out),
                                     (float*)(ws + o_mu), (float*)(ws + o_agg_in),
                                     (float*)(ws + o_agg_out), N);
    k_node<<<gNode, 256, 0, stream>>>(x, (float*)(ws + o_sw_in), (float*)(ws + o_sw_out),
                                      (float*)(ws + o_agg_in), (float*)(ws + o_agg_out),
                                      (float*)(ws + o_c1), (float*)(ws + o_c3),
                                      (float*)(ws + o_Mt), (float*)(ws + o_Wc2t),
                                      (float*)(ws + o_WcompT), (float*)(ws + o_mu),
                                      N, t, t > 0 ? 1 : 0);
  }
  int gPool = ((N + 255) / 256 + 3) / 4;
  k_pool<<<gPool, 256, 0, stream>>>((float*)(ws + o_mu), batch, (float*)(ws + o_pool), N);
  k_poolw6<<<16, 256, 0, stream>>>((float*)(ws + o_pool), W6, (float*)(ws + o_poolw6));
  k_final<<<gN4, 256, 0, stream>>>((float*)(ws + o_mu), batch, (float*)(ws + o_poolw6),
                                   (float*)(ws + o_W7t), W5, out, N);
}

// Round 6
// 1246.599 us; speedup vs baseline: 1.0864x; 1.0077x over previous
//
#include <hip/hip_runtime.h>

#define PD 64
#define BIN_C 6144   // edges staged per block in k_bin (48KB LDS)
#define RB 512       // nodes per bucket (log2 = 9)

// ---------------- phase 1: bin edges by bucket (locality-preserving) ----------------
__global__ __launch_bounds__(256) void k_bin(const int* __restrict__ ei,
    const float* __restrict__ w, uint2* __restrict__ bkt_in, uint2* __restrict__ bkt_out,
    int* __restrict__ bcnt, int E, int K, int cap) {
  __shared__ uint2 staged[BIN_C];
  __shared__ unsigned short bin16[BIN_C];
  __shared__ int cnt[256], base[257], off[256];
  int dir = blockIdx.y;
  const int* __restrict__ keys = dir ? ei : ei + E;
  const int* __restrict__ vals = dir ? ei + E : ei;
  uint2* __restrict__ bdst = dir ? bkt_out : bkt_in;
  int tid = threadIdx.x;
  int e0 = blockIdx.x * BIN_C;
  int count = min(BIN_C, E - e0);
  cnt[tid] = 0;
  __syncthreads();
  for (int i = tid; i < count; i += 256) {
    int b = keys[e0 + i] >> 9;
    bin16[i] = (unsigned short)b;
    atomicAdd(&cnt[b], 1);
  }
  __syncthreads();
  int v = cnt[tid];
  off[tid] = v;
  __syncthreads();
  for (int o = 1; o < 256; o <<= 1) {
    int t = (tid >= o) ? off[tid - o] : 0;
    __syncthreads();
    off[tid] += t;
    __syncthreads();
  }
  base[tid] = off[tid] - v;
  if (tid == 255) base[256] = off[255];
  __syncthreads();
  off[tid] = 0;
  __syncthreads();
  for (int i = tid; i < count; i += 256) {
    int e = e0 + i;
    int k = keys[e];
    int b = bin16[i];
    int l = k & (RB - 1);
    unsigned int packed = ((unsigned int)vals[e] << 9) | (unsigned int)l;
    int p = base[b] + atomicAdd(&off[b], 1);
    staged[p] = make_uint2(packed, __float_as_uint(w[e]));
  }
  __syncthreads();
  if (tid < K) {
    int c = cnt[tid];
    off[tid] = c > 0 ? atomicAdd(&bcnt[dir * K + tid], c) : 0;
  }
  __syncthreads();
  for (int i = tid; i < count; i += 256) {
    int lo = 0, hi = K;
    while (hi - lo > 1) { int mid = (lo + hi) >> 1; if (base[mid] <= i) lo = mid; else hi = mid; }
    int b = lo;
    int rel = off[b] + (i - base[b]);
    if (rel < cap) bdst[(size_t)b * cap + rel] = staged[i];
  }
}

// ---------------- phase 2: per-bucket local CSR ----------------
__global__ __launch_bounds__(256) void k_bucket(
    const uint2* __restrict__ bkt_in, const uint2* __restrict__ bkt_out,
    const int* __restrict__ bcnt,
    int* __restrict__ beg_in, int* __restrict__ end_in,
    int* __restrict__ beg_out, int* __restrict__ end_out,
    float* __restrict__ sw_in, float* __restrict__ sw_out,
    int* __restrict__ col_in, int* __restrict__ col_out,
    int cap, int N, int K) {
  __shared__ int deg[RB], pos[RB], off[RB];
  __shared__ float swl[RB];
  __shared__ int ps[256];
  int b = blockIdx.x, dir = blockIdx.y, tid = threadIdx.x;
  const uint2* __restrict__ bkt = (dir ? bkt_out : bkt_in) + (size_t)b * cap;
  int* __restrict__ beg = dir ? beg_out : beg_in;
  int* __restrict__ end = dir ? end_out : end_in;
  float* __restrict__ swg = dir ? sw_out : sw_in;
  int* __restrict__ col = dir ? col_out : col_in;
  int len = bcnt[dir * K + b];
  if (len > cap) len = cap;
  deg[tid] = 0; deg[tid + 256] = 0;
  swl[tid] = 0.f; swl[tid + 256] = 0.f;
  __syncthreads();
  for (int i = tid; i < len; i += 256) {
    uint2 u = bkt[i];
    int l = u.x & (RB - 1);
    atomicAdd(&deg[l], 1);
    atomicAdd(&swl[l], __uint_as_float(u.y));
  }
  __syncthreads();
  int a0 = deg[2 * tid], a1 = deg[2 * tid + 1];
  ps[tid] = a0 + a1;
  __syncthreads();
  for (int o = 1; o < 256; o <<= 1) {
    int t = (tid >= o) ? ps[tid - o] : 0;
    __syncthreads();
    ps[tid] += t;
    __syncthreads();
  }
  int ex = ps[tid] - (a0 + a1);
  pos[2 * tid] = ex;
  pos[2 * tid + 1] = ex + a0;
  off[tid] = 0; off[tid + 256] = 0;
  __syncthreads();
  int base_node = b << 9;
  size_t colbase = (size_t)b * cap;
  for (int l = tid; l < RB; l += 256) {
    int g = base_node + l;
    if (g < N) {
      beg[g] = (int)(colbase + pos[l]);
      end[g] = (int)(colbase + pos[l] + deg[l]);
      swg[g] = swl[l];
    }
  }
  __syncthreads();
  for (int i = tid; i < len; i += 256) {
    uint2 u = bkt[i];
    int l = u.x & (RB - 1);
    int s = (int)(u.x >> 9);
    int p = pos[l] + atomicAdd(&off[l], 1);
    col[colbase + p] = s;
  }
}

// ---------------- per-step weight folding ----------------
__global__ void k_wprep(const float* __restrict__ W1, const float* __restrict__ W2,
                        const float* __restrict__ W3, const float* __restrict__ W4,
                        const float* __restrict__ Wc1, const float* __restrict__ Wc2,
                        const float* __restrict__ Wcomp, const float* __restrict__ W7,
                        float* c1, float* c3, float* Mt, float* Wc2t,
                        float* WcompT, float* W7t) {
  int t = blockIdx.x;
  int tid = threadIdx.x;
  __shared__ float r4[64], v3[64];
  if (tid < 64) r4[tid] = fmaxf(W4[t * 64 + tid], 0.f);
  __syncthreads();
  if (tid < 64) {
    float s = 0.f;
    for (int k = 0; k < 64; ++k) s += W3[t * 4096 + tid * 64 + k] * r4[k];
    v3[tid] = s;
    float s1 = 0.f;
    for (int k = 0; k < 64; ++k) s1 += Wc1[t * 12288 + tid * 192 + k] * W1[t * 64 + k];
    c1[t * 64 + tid] = s1;
  }
  __syncthreads();
  if (tid < 64) {
    float s = 0.f;
    for (int k = 0; k < 64; ++k) s += Wc1[t * 12288 + tid * 192 + 128 + k] * v3[k];
    c3[t * 64 + tid] = s;
  }
  for (int idx = tid; idx < 4096; idx += 256) {
    int j = idx >> 6, p = idx & 63;
    float s = 0.f;
    for (int k = 0; k < 64; ++k)
      s += Wc1[t * 12288 + p * 192 + 64 + k] * W2[t * 4096 + k * 64 + j];
    Mt[t * 4096 + idx] = s;
    Wc2t[t * 4096 + idx] = Wc2[t * 4096 + p * 64 + j];
  }
  if (t == 0) {
    for (int idx = tid; idx < 8192; idx += 256) {
      int j = idx >> 6, p = idx & 63;
      WcompT[idx] = Wcomp[p * 128 + j];
    }
    for (int idx = tid; idx < 4096; idx += 256) {
      int j = idx >> 6, p = idx & 63;
      W7t[idx] = W7[p * 64 + j];
    }
  }
}

// ---------------- edge aggregation (gather over CSR, ILP=8) ----------------
__global__ __launch_bounds__(256) void k_agg(
    const int* __restrict__ beg_in, const int* __restrict__ end_in,
    const int* __restrict__ col_in,
    const int* __restrict__ beg_out, const int* __restrict__ end_out,
    const int* __restrict__ col_out,
    const float* __restrict__ mu, float* __restrict__ agg_in,
    float* __restrict__ agg_out, int n) {
  int wave = (blockIdx.x * blockDim.x + threadIdx.x) >> 6;
  int lane = threadIdx.x & 63;
  if (wave >= n) return;
#pragma unroll
  for (int dir = 0; dir < 2; ++dir) {
    const int* __restrict__ bega = dir ? beg_out : beg_in;
    const int* __restrict__ enda = dir ? end_out : end_in;
    const int* __restrict__ col = dir ? col_out : col_in;
    float* __restrict__ agg = dir ? agg_out : agg_in;
    int b = bega[wave], e = enda[wave];
    float a0 = 0.f, a1 = 0.f, a2 = 0.f, a3 = 0.f;
    if (b < e) {
      int last = e - 1;
      for (int k = b; k < e; k += 8) {
        int idx[8];
        float msk[8];
#pragma unroll
        for (int i = 0; i < 8; ++i) {
          int kk = k + i;
          idx[i] = col[kk <= last ? kk : last];
          msk[i] = (kk <= last) ? 1.f : 0.f;
        }
        float v[8];
#pragma unroll
        for (int i = 0; i < 8; ++i)
          v[i] = mu[(size_t)idx[i] * 64 + lane];
        a0 = fmaf(msk[0], v[0], a0);
        a1 = fmaf(msk[1], v[1], a1);
        a2 = fmaf(msk[2], v[2], a2);
        a3 = fmaf(msk[3], v[3], a3);
        a0 = fmaf(msk[4], v[4], a0);
        a1 = fmaf(msk[5], v[5], a1);
        a2 = fmaf(msk[6], v[6], a2);
        a3 = fmaf(msk[7], v[7], a3);
      }
    }
    agg[(size_t)wave * 64 + lane] = (a0 + a1) + (a2 + a3);
  }
}

// ---------------- fused per-node GEMM chain: lane = node, register z, uniform W ----
// lane = node. Activations z[p] live in registers; weights are WAVE-UNIFORM global
// loads (L1-broadcast / s_load). The per-wave LDS tile is used ONLY as a 16KB
// transpose buffer (z written acc-indexed, read j-indexed): 64 ds_write_b32 +
// 64 ds_read_b32 per gemm, conflict-free, no __syncthreads anywhere.
__device__ __forceinline__ void stage_row_to_tile(const float* __restrict__ row,
                                                  float* tz, int lane) {
  const float4* ar = (const float4*)row;
#pragma unroll
  for (int q = 0; q < 16; ++q) {
    float4 v = ar[q];
    tz[(4 * q + 0) * 64 + lane] = v.x;
    tz[(4 * q + 1) * 64 + lane] = v.y;
    tz[(4 * q + 2) * 64 + lane] = v.z;
    tz[(4 * q + 3) * 64 + lane] = v.w;
  }
}

__device__ __forceinline__ void gemm_t(const float* __restrict__ W, const float* tz,
                                       int lane, float acc[64]) {
  for (int jo = 0; jo < 8; ++jo) {      // dynamic: keeps I$ footprint ~5KB/gemm
#pragma unroll
    for (int ji = 0; ji < 8; ++ji) {
      int j = jo * 8 + ji;
      float a = tz[j * 64 + lane];                       // ds_read_b32, conflict-free
      const float4* wr = (const float4*)(W + j * 64);    // wave-uniform
#pragma unroll
      for (int p4 = 0; p4 < 16; ++p4) {
        float4 wv = wr[p4];
        acc[4 * p4 + 0] = fmaf(a, wv.x, acc[4 * p4 + 0]);
        acc[4 * p4 + 1] = fmaf(a, wv.y, acc[4 * p4 + 1]);
        acc[4 * p4 + 2] = fmaf(a, wv.z, acc[4 * p4 + 2]);
        acc[4 * p4 + 3] = fmaf(a, wv.w, acc[4 * p4 + 3]);
      }
    }
  }
}

__device__ __forceinline__ void half_pass(
    const float* __restrict__ sw, const float* __restrict__ aggbase,
    const float* __restrict__ Mt, const float* __restrict__ C2,
    const float* __restrict__ Cmp, const float4* __restrict__ c1r,
    const float4* __restrict__ c3r, float xv, int nc, int lane, float* tz,
    int haveAgg, float o[64]) {
  float zz[64];
  float swv = sw[nc];
#pragma unroll
  for (int q = 0; q < 16; ++q) {
    float4 a = c1r[q], b = c3r[q];
    zz[4 * q + 0] = xv * a.x + swv * b.x;
    zz[4 * q + 1] = xv * a.y + swv * b.y;
    zz[4 * q + 2] = xv * a.z + swv * b.z;
    zz[4 * q + 3] = xv * a.w + swv * b.w;
  }
  if (haveAgg) {
    stage_row_to_tile(aggbase + (size_t)nc * 64, tz, lane);
    __builtin_amdgcn_wave_barrier();
    gemm_t(Mt, tz, lane, zz);
  }
#pragma unroll
  for (int p = 0; p < 64; ++p) tz[p * 64 + lane] = fmaxf(zz[p], 0.f);
  __builtin_amdgcn_wave_barrier();
#pragma unroll
  for (int p = 0; p < 64; ++p) zz[p] = 0.f;
  gemm_t(C2, tz, lane, zz);
  __builtin_amdgcn_wave_barrier();
#pragma unroll
  for (int p = 0; p < 64; ++p) tz[p * 64 + lane] = fmaxf(zz[p], 0.f);
  __builtin_amdgcn_wave_barrier();
  gemm_t(Cmp, tz, lane, o);
}

__global__ __launch_bounds__(256, 2) void k_node(
    const float* __restrict__ x, const float* __restrict__ sw_in,
    const float* __restrict__ sw_out, const float* __restrict__ agg_in,
    const float* __restrict__ agg_out, const float* __restrict__ c1g,
    const float* __restrict__ c3g, const float* __restrict__ Mtg,
    const float* __restrict__ Wc2tg, const float* __restrict__ WcompTg,
    float* __restrict__ mu, int n, int t, int haveAgg) {
  __shared__ float tileZ[4][4096];   // 64KB -> 2 blocks/CU; wave-private quarters
  int tid = threadIdx.x, lane = tid & 63, w = tid >> 6;
  int node0 = blockIdx.x * 256 + w * 64;
  if (node0 >= n) return;            // wave-uniform; no block barriers exist
  int nd = node0 + lane;
  bool act = nd < n;
  int nc = act ? nd : n - 1;
  float xv = x[nc];
  float* tz = tileZ[w];
  const float* Mt = Mtg + t * 4096;
  const float* C2 = Wc2tg + t * 4096;
  const float4* c1r = (const float4*)(c1g + t * 64);
  const float4* c3r = (const float4*)(c3g + t * 64);
  float o[64];
#pragma unroll
  for (int p = 0; p < 64; ++p) o[p] = 0.f;

  half_pass(sw_in, agg_in, Mt, C2, WcompTg, c1r, c3r, xv, nc, lane, tz, haveAgg, o);
  half_pass(sw_out, agg_out, Mt, C2, WcompTg + 4096, c1r, c3r, xv, nc, lane, tz, haveAgg, o);

  if (act) {
    float4* dst = (float4*)(mu + (size_t)nd * 64);
#pragma unroll
    for (int q = 0; q < 16; ++q)
      dst[q] = make_float4(fmaxf(o[4 * q + 0], 0.f), fmaxf(o[4 * q + 1], 0.f),
                           fmaxf(o[4 * q + 2], 0.f), fmaxf(o[4 * q + 3], 0.f));
  }
}

// ---------------- pooling ----------------
__global__ __launch_bounds__(256) void k_pool(
    const float* __restrict__ mu, const int* __restrict__ batch,
    float* __restrict__ pool, int n) {
  int gw = (blockIdx.x * blockDim.x + threadIdx.x) >> 6;
  int lane = threadIdx.x & 63;
  int start = gw * 256;
  if (start >= n) return;
  int end = min(start + 256, n);
  int cur = batch[start];
  float acc = 0.f;
  for (int i = start; i < end; ++i) {
    int b = batch[i];
    if (b != cur) {
      atomicAdd(&pool[cur * 64 + lane], acc);
      acc = 0.f;
      cur = b;
    }
    acc += mu[(size_t)i * 64 + lane];
  }
  atomicAdd(&pool[cur * 64 + lane], acc);
}

__global__ void k_poolw6(const float* __restrict__ pool, const float* __restrict__ W6,
                         float* __restrict__ out) {
  int idx = blockIdx.x * blockDim.x + threadIdx.x;  // < 4096
  int g = idx >> 6, p = idx & 63;
  float s = 0.f;
  for (int k = 0; k < 64; ++k) s += pool[g * 64 + k] * W6[p * 64 + k];
  out[idx] = s;
}

// ---------------- head ----------------
__global__ __launch_bounds__(256) void k_final(
    const float* __restrict__ mu, const int* __restrict__ batch,
    const float* __restrict__ poolw6, const float* __restrict__ W7t,
    const float* __restrict__ W5, float* __restrict__ out, int n) {
  __shared__ float S[4][64];
  int tid = threadIdx.x, lane = tid & 63, w = tid >> 6;
  int node = blockIdx.x * 4 + w;
  if (node >= n) return;
  float mv = mu[(size_t)node * 64 + lane];
  S[w][lane] = mv;
  __builtin_amdgcn_wave_barrier();
  int g = batch[node];
  float t1 = fmaxf(poolw6[g * 64 + lane], 0.f);
  float acc = 0.f;
#pragma unroll 8
  for (int j = 0; j < 64; ++j) acc = fmaf(S[w][j], W7t[j * 64 + lane], acc);
  float t2 = fmaxf(acc, 0.f);
  float val = W5[lane] * t1 + W5[64 + lane] * t2;
  for (int off = 32; off > 0; off >>= 1) val += __shfl_down(val, off);
  if (lane == 0) out[node] = fmaxf(val, 0.f);
}

extern "C" void kernel_launch(void* const* d_in, const int* in_sizes, int n_in,
                              void* d_out, int out_size, void* d_ws, size_t ws_size,
                              hipStream_t stream) {
  const float* x = (const float*)d_in[0];
  const float* weight = (const float*)d_in[1];
  const int* ei = (const int*)d_in[2];
  const int* batch = (const int*)d_in[3];
  const float* W1 = (const float*)d_in[4];
  const float* W2 = (const float*)d_in[5];
  const float* W3 = (const float*)d_in[6];
  const float* W4 = (const float*)d_in[7];
  const float* Wc1 = (const float*)d_in[8];
  const float* Wc2 = (const float*)d_in[9];
  const float* Wcomp = (const float*)d_in[10];
  const float* W5 = (const float*)d_in[11];
  const float* W6 = (const float*)d_in[12];
  const float* W7 = (const float*)d_in[13];
  float* out = (float*)d_out;
  int N = in_sizes[0];
  int E = in_sizes[1];
  int T = in_sizes[4] / 64;

  int K = (N + RB - 1) / RB;
  int cap = E / K + E / (4 * K) + 1024;
  int Nw = ((N + 63) / 64) * 64;

  char* ws = (char*)d_ws;
  size_t off = 0;
  auto alloc = [&](size_t bytes) {
    size_t o = off;
    off += (bytes + 255) & ~(size_t)255;
    return o;
  };
  // zeroed region
  size_t o_bcnt = alloc((size_t)2 * K * 4);
  size_t o_pool = alloc(4096 * 4);
  size_t zero_end = off;
  size_t o_beg_in = alloc((size_t)N * 4);
  size_t o_end_in = alloc((size_t)N * 4);
  size_t o_beg_out = alloc((size_t)N * 4);
  size_t o_end_out = alloc((size_t)N * 4);
  size_t o_sw_in = alloc((size_t)N * 4);
  size_t o_sw_out = alloc((size_t)N * 4);
  size_t o_col_in = alloc((size_t)K * cap * 4);
  size_t o_col_out = alloc((size_t)K * cap * 4);
  size_t o_mu = alloc((size_t)Nw * 64 * 4);
  size_t aggBytes = (size_t)Nw * 64 * 4;
  size_t bktBytes = (size_t)K * cap * 8;
  size_t big = aggBytes > bktBytes ? aggBytes : bktBytes;
  size_t o_agg_in = alloc(big);   // aliased: bkt_in during build
  size_t o_agg_out = alloc(big);  // aliased: bkt_out during build
  size_t o_c1 = alloc(4 * 64 * 4);
  size_t o_c3 = alloc(4 * 64 * 4);
  size_t o_Mt = alloc(4 * 4096 * 4);
  size_t o_Wc2t = alloc(4 * 4096 * 4);
  size_t o_WcompT = alloc(8192 * 4);
  size_t o_W7t = alloc(4096 * 4);
  size_t o_poolw6 = alloc(4096 * 4);
  (void)ws_size; (void)n_in; (void)out_size;

  hipMemsetAsync(ws, 0, zero_end, stream);

  dim3 gBin((E + BIN_C - 1) / BIN_C, 2);
  k_bin<<<gBin, 256, 0, stream>>>(ei, weight, (uint2*)(ws + o_agg_in),
                                  (uint2*)(ws + o_agg_out), (int*)(ws + o_bcnt),
                                  E, K, cap);
  dim3 gBkt(K, 2);
  k_bucket<<<gBkt, 256, 0, stream>>>((uint2*)(ws + o_agg_in), (uint2*)(ws + o_agg_out),
                                     (int*)(ws + o_bcnt),
                                     (int*)(ws + o_beg_in), (int*)(ws + o_end_in),
                                     (int*)(ws + o_beg_out), (int*)(ws + o_end_out),
                                     (float*)(ws + o_sw_in), (float*)(ws + o_sw_out),
                                     (int*)(ws + o_col_in), (int*)(ws + o_col_out),
                                     cap, N, K);
  k_wprep<<<T, 256, 0, stream>>>(W1, W2, W3, W4, Wc1, Wc2, Wcomp, W7,
                                 (float*)(ws + o_c1), (float*)(ws + o_c3),
                                 (float*)(ws + o_Mt), (float*)(ws + o_Wc2t),
                                 (float*)(ws + o_WcompT), (float*)(ws + o_W7t));

  int gN4 = (N + 3) / 4;
  int gNode = (N + 255) / 256;
  for (int t = 0; t < T; ++t) {
    if (t > 0)
      k_agg<<<gN4, 256, 0, stream>>>((int*)(ws + o_beg_in), (int*)(ws + o_end_in),
                                     (int*)(ws + o_col_in),
                                     (int*)(ws + o_beg_out), (int*)(ws + o_end_out),
                                     (int*)(ws + o_col_out),
                                     (float*)(ws + o_mu), (float*)(ws + o_agg_in),
                                     (float*)(ws + o_agg_out), N);
    k_node<<<gNode, 256, 0, stream>>>(x, (float*)(ws + o_sw_in), (float*)(ws + o_sw_out),
                                      (float*)(ws + o_agg_in), (float*)(ws + o_agg_out),
                                      (float*)(ws + o_c1), (float*)(ws + o_c3),
                                      (float*)(ws + o_Mt), (float*)(ws + o_Wc2t),
                                      (float*)(ws + o_WcompT), (float*)(ws + o_mu),
                                      N, t, t > 0 ? 1 : 0);
  }
  int gPool = ((N + 255) / 256 + 3) / 4;
  k_pool<<<gPool, 256, 0, stream>>>((float*)(ws + o_mu), batch, (float*)(ws + o_pool), N);
  k_poolw6<<<16, 256, 0, stream>>>((float*)(ws + o_pool), W6, (float*)(ws + o_poolw6));
  k_final<<<gN4, 256, 0, stream>>>((float*)(ws + o_mu), batch, (float*)(ws + o_poolw6),
                                   (float*)(ws + o_W7t), W5, out, N);
}